// Round 7
// baseline (92.435 us; speedup 1.0000x reference)
//
#include <hip/hip_runtime.h>

// QueryAndGroupRRI: B=4, N=16384, M=2048, nsample=32, radius=0.1
// Inputs (float32): xyz (4,16384,3), new_xyz (4,2048,3)
// Output (float32): (4, 33, 2048, 32)  [dis_sort rows 0..31, grouped_r row 32]
//
// R16: decoupled phase mapping in the query kernel. 512-thr blocks, 8 waves:
//   phase 1: wave i scans ONE query's concatenated candidate stream (~6
//     rounds, half of R14's 12 serial rounds/wave) into s_hit[i]; 8192 waves
//     -> 32 waves/CU during phase 1 (2x latency hiding; R14 was grid-limited
//     to 16 waves/CU, Occ 36%).
//   __syncthreads, hit counts handed off via s_hitcnt[8].
//   phase 2: waves 0..3 run the byte-identical R14 pair code (2 queries per
//     wave, 32-lane halves); waves 4..7 exit. No duplicated phase-2 work
//     (R13's mistake). Phase-1/phase-2 math byte-identical per query.
// Build identical to R15 (k_count_scan + R9-verified k_scatter).
// R15 lesson: build swaps are total-neutral; query is the attackable chunk.

#define BB 4
#define NN 16384
#define MM 2048
#define NS 32
#define R2 0.01f
#define GZ 20          // z slabs
#define NCELL 2000     // 10*10*20
#define CPAD 2048
#define HCAP 128       // per-query hit cap (lambda~68, +7sigma safe)

// ws layout: off int[4][2048] @0 | cur @32KB | pts @96KB
#define WS_CUR_OFF (32 * 1024)
#define WS_PTS_OFF (96 * 1024)
#define WS_NEED (WS_PTS_OFF + (size_t)BB * NN * 16)

__device__ __forceinline__ int cell_of(float x, float y, float z) {
    int ci = (int)(x * 10.0f); ci = ci < 0 ? 0 : (ci > 9 ? 9 : ci);
    int cj = (int)(y * 10.0f); cj = cj < 0 ? 0 : (cj > 9 ? 9 : cj);
    int ck = (int)(z * 20.0f); ck = ck < 0 ? 0 : (ck > 19 ? 19 : ck);
    return (ci * 10 + cj) * GZ + ck;
}

// ---- build stage 1: fused count+scan, one block per batch (R15 verified) ----
__global__ __launch_bounds__(1024) void k_count_scan(const float* __restrict__ xyz,
                                                     int* __restrict__ off,
                                                     int* __restrict__ cur) {
    __shared__ int hist[CPAD];    // 8 KB
    __shared__ int wsum[16];

    const int b = blockIdx.x;
    const int t = threadIdx.x;
    const int lane = t & 63, wid = t >> 6;
    const float4* __restrict__ xb4 = (const float4*)(xyz + (size_t)b * NN * 3);

    hist[t] = 0;
    hist[t + 1024] = 0;
    __syncthreads();

    // histogram: 4 pts/thread/iter via 3 float4 loads (verified R12 pass 1)
    #pragma unroll
    for (int it = 0; it < 4; ++it) {
        const int f = (it * 1024 + t) * 3;
        float4 a = xb4[f];
        float4 g = xb4[f + 1];
        float4 c = xb4[f + 2];
        atomicAdd(&hist[cell_of(a.x, a.y, a.z)], 1);
        atomicAdd(&hist[cell_of(a.w, g.x, g.y)], 1);
        atomicAdd(&hist[cell_of(g.z, g.w, c.x)], 1);
        atomicAdd(&hist[cell_of(c.y, c.z, c.w)], 1);
    }
    __syncthreads();

    // exclusive scan of hist[0..2047]: 2 cells/thread (verified R12 scan)
    const int v0 = hist[2 * t];
    const int v1 = hist[2 * t + 1];
    const int s = v0 + v1;
    int xs = s;
    #pragma unroll
    for (int o = 1; o < 64; o <<= 1) {
        int u = __shfl_up(xs, o);
        if (lane >= o) xs += u;
    }
    if (lane == 63) wsum[wid] = xs;
    __syncthreads();
    int pre = 0;
    #pragma unroll
    for (int i2 = 0; i2 < 16; ++i2) pre += (i2 < wid) ? wsum[i2] : 0;
    const int excl = pre + xs - s;
    off[b * CPAD + 2 * t] = excl;
    off[b * CPAD + 2 * t + 1] = excl + v0;
    cur[b * CPAD + 2 * t] = excl;
    cur[b * CPAD + 2 * t + 1] = excl + v0;
}

// ---- build stage 2: R9's verified scatter (global-atomic cur) ----
__global__ __launch_bounds__(256) void k_scatter(const float* __restrict__ xyz,
                                                 int* __restrict__ cur,
                                                 float4* __restrict__ pts) {
    int i = blockIdx.x * 256 + threadIdx.x;   // 0..65535
    int b = i >> 14;
    const float* p = xyz + (size_t)i * 3;
    float x = p[0], y = p[1], z = p[2];
    int pos = atomicAdd(&cur[b * CPAD + cell_of(x, y, z)], 1);
    pts[(size_t)b * NN + pos] = make_float4(x, y, z, __int_as_float(i & (NN - 1)));
}

// ---- R16 query: 8 waves; phase1 = 1 query/wave; phase2 = R14 pair code ----
__global__ __launch_bounds__(512) void qgr_grid_kernel(
    const float* __restrict__ xyz,
    const float* __restrict__ nxyz,
    const int* __restrict__ offi,
    const float4* __restrict__ pts,
    float* __restrict__ out) {

    __shared__ float4 s_hit[8][HCAP];      // 16 KB: hit (x,y,z,idx-bits)
    __shared__ float4 s_sel[4][2][NS];     // 4 KB: selected 32, slot order
    __shared__ int s_hitcnt[8];

    const int lane = threadIdx.x & 63;
    const int wv = threadIdx.x >> 6;           // 0..7
    const unsigned long long lmask = (1ull << lane) - 1ull;

    const int qbase = blockIdx.x * 8;          // 8 queries per block, same batch
    const int b = qbase >> 11;
    const int* offb = offi + b * CPAD;
    const float4* ptsb = pts + (size_t)b * NN;
    const float* xb = xyz + (size_t)b * NN * 3;

    // ---- phase 1: each wave scans ONE query's concatenated stream ----
    {
        const int q = qbase + wv;
        const float* nqw = nxyz + (size_t)q * 3;
        const float ccx = nqw[0], ccy = nqw[1], ccz = nqw[2];

        int ci0 = (int)(ccx * 10.0f); ci0 = ci0 < 0 ? 0 : (ci0 > 9 ? 9 : ci0);
        int cj0 = (int)(ccy * 10.0f); cj0 = cj0 < 0 ? 0 : (cj0 > 9 ? 9 : cj0);
        int ck0 = (int)(ccz * 20.0f); ck0 = ck0 < 0 ? 0 : (ck0 > 19 ? 19 : ck0);
        int zlo = ck0 > 2 ? ck0 - 2 : 0;
        int zhi = ck0 < 17 ? ck0 + 2 : 19;

        // 9 candidate columns in fixed (di,dj) order; zero-length if off-grid.
        int rs[9], rl[9], pref[10];
        pref[0] = 0;
        #pragma unroll
        for (int di = -1; di <= 1; ++di) {
            #pragma unroll
            for (int dj = -1; dj <= 1; ++dj) {
                const int k = (di + 1) * 3 + (dj + 1);
                int ii = ci0 + di, jj = cj0 + dj;
                bool ok = ((unsigned)ii <= 9u) && ((unsigned)jj <= 9u);
                int base2 = ok ? (ii * 10 + jj) * GZ : 0;
                int s0 = offb[base2 + zlo];
                int e0 = offb[base2 + zhi + 1];
                rs[k] = s0;
                rl[k] = ok ? (e0 - s0) : 0;
                pref[k + 1] = pref[k] + rl[k];
            }
        }
        const int T = pref[9];   // total candidates (wave-uniform)

        int hits = 0;
        float4 cur;
        bool valid = lane < T;
        {
            const int p = lane;
            int a = rs[0] + p;
            #pragma unroll
            for (int r = 1; r < 9; ++r)
                a = (p >= pref[r]) ? (rs[r] + (p - pref[r])) : a;
            cur = ptsb[valid ? a : 0];
        }
        for (int base = 0; base < T; base += 64) {
            float4 nxt = cur;
            bool nvalid = false;
            if (base + 64 < T) {
                const int p = base + 64 + lane;
                nvalid = p < T;
                int a = rs[0] + p;
                #pragma unroll
                for (int r = 1; r < 9; ++r)
                    a = (p >= pref[r]) ? (rs[r] + (p - pref[r])) : a;
                nxt = ptsb[nvalid ? a : 0];
            }
            float dx = __fsub_rn(ccx, cur.x);
            float dy = __fsub_rn(ccy, cur.y);
            float dz = __fsub_rn(ccz, cur.z);
            float d2 = __fadd_rn(__fadd_rn(__fmul_rn(dx, dx), __fmul_rn(dy, dy)),
                                 __fmul_rn(dz, dz));
            bool hit = valid && (d2 < R2);
            unsigned long long bal = __ballot(hit);
            if (bal) {
                int rank = __popcll(bal & lmask);
                int slot = hits + rank;
                if (hit && slot < HCAP) s_hit[wv][slot] = cur;
                hits += __popcll(bal);
            }
            cur = nxt;
            valid = nvalid;
        }
        if (lane == 0) s_hitcnt[wv] = hits;
    }

    __syncthreads();

    // ---- phase 2: waves 0..3 run the R14 pair code; waves 4..7 exit ----
    if (threadIdx.x >= 256) return;

    const int w = wv;                 // 0..3
    const int sub = lane & 31;
    const int half = lane >> 5;
    const int q0 = qbase + w * 2;

    const float* nq = nxyz + (size_t)q0 * 3;
    const float cx0 = nq[0], cy0 = nq[1], cz0 = nq[2];
    const float cx1 = nq[3], cy1 = nq[4], cz1 = nq[5];

    const int hwv = 2 * w + half;     // which phase-1 wave's hits
    const int hits = s_hitcnt[hwv];
    const int cap = hits < HCAP ? hits : HCAP;
    const float ccx = half ? cx1 : cx0;
    const float ccy = half ? cy1 : cy0;
    const float ccz = half ? cz1 : cz0;

    // 128-elem bitonic in 4 regs x 32 lanes (verified R7); key = idx<<8 | slot
    int key[4];
    #pragma unroll
    for (int r = 0; r < 4; ++r) {
        int e = r * 32 + sub;
        int idx_e = __float_as_int(s_hit[hwv][e].w);
        key[r] = (e < cap) ? ((idx_e << 8) | e) : 0x7fffffff;
    }

    #pragma unroll
    for (int k = 2; k <= 16; k <<= 1) {
        #pragma unroll
        for (int j = k >> 1; j > 0; j >>= 1) {
            bool lower = (sub & j) == 0;
            bool asc = (sub & k) == 0;
            bool keepmin = (lower == asc);
            #pragma unroll
            for (int r = 0; r < 4; ++r) {
                int p = __shfl_xor(key[r], j);
                key[r] = keepmin ? min(key[r], p) : max(key[r], p);
            }
        }
    }
    #pragma unroll
    for (int j = 16; j > 0; j >>= 1) {
        bool lower = (sub & j) == 0;
        #pragma unroll
        for (int r = 0; r < 4; ++r) {
            int p = __shfl_xor(key[r], j);
            bool asc = (r & 1) == 0;
            key[r] = (lower == asc) ? min(key[r], p) : max(key[r], p);
        }
    }
    {
        int t0 = min(key[0], key[1]); key[1] = max(key[0], key[1]); key[0] = t0;
        int t2 = max(key[2], key[3]); key[3] = min(key[2], key[3]); key[2] = t2;
    }
    #pragma unroll
    for (int j = 16; j > 0; j >>= 1) {
        bool lower = (sub & j) == 0;
        #pragma unroll
        for (int r = 0; r < 4; ++r) {
            int p = __shfl_xor(key[r], j);
            bool asc = (r & 2) == 0;
            key[r] = (lower == asc) ? min(key[r], p) : max(key[r], p);
        }
    }
    {
        int t0 = min(key[0], key[2]); key[2] = max(key[0], key[2]); key[0] = t0;
        int t1 = min(key[1], key[3]); key[3] = max(key[1], key[3]); key[1] = t1;
        t0 = min(key[0], key[1]); key[1] = max(key[0], key[1]); key[0] = t0;
        t1 = min(key[2], key[3]); key[3] = max(key[2], key[3]); key[2] = t1;
    }
    #pragma unroll
    for (int j = 16; j > 0; j >>= 1) {
        bool lower = (sub & j) == 0;
        #pragma unroll
        for (int r = 0; r < 4; ++r) {
            int p = __shfl_xor(key[r], j);
            key[r] = lower ? min(key[r], p) : max(key[r], p);
        }
    }

    // fetch selected points (smallest 32 indices, ascending), pad with slot 0
    const int found = hits < NS ? hits : NS;
    const int hbase = half << 5;
    float4 sel = make_float4(0.f, 0.f, 0.f, 0.f);
    if (sub < found) sel = s_hit[hwv][key[0] & 0xFF];
    float p0x, p0y, p0z;
    if (found == 0) { p0x = xb[0]; p0y = xb[1]; p0z = xb[2]; }
    else {
        p0x = __shfl(sel.x, hbase); p0y = __shfl(sel.y, hbase); p0z = __shfl(sel.z, hbase);
    }
    if (sub >= found) { sel.x = p0x; sel.y = p0y; sel.z = p0z; }
    const float hx = sel.x, hy = sel.y, hz = sel.z;

    // stage selected pts for broadcast reads
    s_sel[w][half][sub] = sel;

    // dis column j=sub via ds_read_b128 broadcasts (exact np op order)
    float v[NS];
    #pragma unroll
    for (int ii = 0; ii < NS; ++ii) {
        float4 B = s_sel[w][half][ii];
        float dx = __fsub_rn(B.x, hx);
        float dy = __fsub_rn(B.y, hy);
        float dz = __fsub_rn(B.z, hz);
        v[ii] = sqrtf(__fadd_rn(__fadd_rn(__fmul_rn(dx, dx), __fmul_rn(dy, dy)),
                                __fmul_rn(dz, dz)));
    }

    // row-sub sum in numpy pairwise-8 order; half-local argmax, first-occurrence
    float r8[8];
    #pragma unroll
    for (int t = 0; t < 8; ++t) {
        r8[t] = __fadd_rn(__fadd_rn(__fadd_rn(v[t], v[t + 8]), v[t + 16]), v[t + 24]);
    }
    float mv = __fadd_rn(__fadd_rn(__fadd_rn(r8[0], r8[1]), __fadd_rn(r8[2], r8[3])),
                         __fadd_rn(__fadd_rn(r8[4], r8[5]), __fadd_rn(r8[6], r8[7])));
    int mi = sub;
    #pragma unroll
    for (int off = 1; off < 32; off <<= 1) {
        float ov = __shfl_xor(mv, off);
        int oi = __shfl_xor(mi, off);
        if (ov > mv || (ov == mv && oi < mi)) { mv = ov; mi = oi; }
    }

    float4 T = s_sel[w][half][mi];
    const float tx = T.x, ty = T.y, tz = T.z;

    float ux = ccy * tz - ccz * ty, uy = ccz * tx - ccx * tz, uz = ccx * ty - ccy * tx;
    float vx = uy * ccz - uz * ccy, vy = uz * ccx - ux * ccz, vz = ux * ccy - uy * ccx;
    float vn = fmaxf(sqrtf(vx * vx + vy * vy + vz * vz), 1e-37f);
    float tnx = vx / vn, tny = vy / vn, tnz = vz / vn;

    float nrm = sqrtf(ccx * ccx + ccy * ccy + ccz * ccz);
    float dn = nrm + 1e-8f;
    float nnx = ccx / dn, nny = ccy / dn, nnz = ccz / dn;

    float ax = ccy * hz - ccz * hy, ay = ccz * hx - ccx * hz, az = ccx * hy - ccy * hx;
    float px = ay * ccz - az * ccy, py = az * ccx - ax * ccz, pz = ax * ccy - ay * ccx;
    float pn = fmaxf(sqrtf(px * px + py * py + pz * pz), 1e-37f);
    px /= pn; py /= pn; pz /= pn;

    float qx = py * tnz - pz * tny;
    float qy = pz * tnx - px * tnz;
    float qz = px * tny - py * tnx;
    float sinv = qx * nnx + qy * nny + qz * nnz;

    float gr = sqrtf(hx * hx + hy * hy + hz * hz);

    const int m_h = (q0 + half) & (MM - 1);
    const size_t rowstride = (size_t)MM * NS;
    const size_t obase = (((size_t)b * 33) * MM + m_h) * NS + sub;
    out[obase + 32 * rowstride] = gr;

    // per-lane ascending sort: Batcher odd-even mergesort, min/max CEs
    #pragma unroll
    for (int p = 1; p < NS; p <<= 1) {
        #pragma unroll
        for (int k = p; k >= 1; k >>= 1) {
            #pragma unroll
            for (int j = k & (p - 1); j + k < NS; j += 2 * k) {
                #pragma unroll
                for (int i = 0; i < k; ++i) {
                    if (i + j + k < NS) {
                        int x = i + j, y = i + j + k;
                        if ((x / (2 * p)) == (y / (2 * p))) {
                            float lo = fminf(v[x], v[y]);
                            v[y] = fmaxf(v[x], v[y]);
                            v[x] = lo;
                        }
                    }
                }
            }
        }
    }

    #pragma unroll
    for (int ii = 0; ii < NS; ++ii)
        out[obase + (size_t)ii * rowstride] = v[ii] * sinv;
}

// ---------------- fallback: verified brute-force scan (round-4) ----------------
#define CHUNKS 4
__global__ __launch_bounds__(256) void qgr_kernel(
    const float* __restrict__ xyz,
    const float* __restrict__ nxyz,
    float* __restrict__ out) {

    __shared__ float s_gx[4][NS], s_gy[4][NS], s_gz[4][NS];
    __shared__ float s_dis[4][NS][NS + 1];

    const int lane = threadIdx.x & 63;
    const int w = threadIdx.x >> 6;
    const int q = blockIdx.x * 4 + w;
    const int b = q >> 11;
    const int m = q & (MM - 1);

    const float* xb = xyz + (size_t)b * NN * 3;
    const float* nq = nxyz + (size_t)q * 3;
    const float cx = nq[0], cy = nq[1], cz = nq[2];
    const unsigned long long lmask = (1ull << lane) - 1ull;

    int cnt = 0;
    for (int base = 0; base < NN; base += 64 * CHUNKS) {
        float X[CHUNKS], Y[CHUNKS], Z[CHUNKS];
        #pragma unroll
        for (int c = 0; c < CHUNKS; ++c) {
            const float* p = xb + (size_t)(base + c * 64 + lane) * 3;
            X[c] = p[0]; Y[c] = p[1]; Z[c] = p[2];
        }
        bool in[CHUNKS];
        #pragma unroll
        for (int c = 0; c < CHUNKS; ++c) {
            float dx = __fsub_rn(cx, X[c]);
            float dy = __fsub_rn(cy, Y[c]);
            float dz = __fsub_rn(cz, Z[c]);
            float d2 = __fadd_rn(__fadd_rn(__fmul_rn(dx, dx), __fmul_rn(dy, dy)),
                                 __fmul_rn(dz, dz));
            in[c] = d2 < R2;
        }
        #pragma unroll
        for (int c = 0; c < CHUNKS; ++c) {
            unsigned long long bal = __ballot(in[c]);
            if (bal) {
                int rank = __popcll(bal & lmask);
                int slot = cnt + rank;
                if (in[c] && slot < NS) {
                    s_gx[w][slot] = X[c]; s_gy[w][slot] = Y[c]; s_gz[w][slot] = Z[c];
                }
                cnt += __popcll(bal);
            }
        }
        if (cnt >= NS) break;
    }
    __syncthreads();

    int found = cnt < NS ? cnt : NS;
    float p0x, p0y, p0z;
    if (found == 0) { p0x = xb[0]; p0y = xb[1]; p0z = xb[2]; }
    else            { p0x = s_gx[w][0]; p0y = s_gy[w][0]; p0z = s_gz[w][0]; }
    if (lane < NS && lane >= found) {
        s_gx[w][lane] = p0x; s_gy[w][lane] = p0y; s_gz[w][lane] = p0z;
    }
    __syncthreads();

    #pragma unroll
    for (int t = 0; t < 16; ++t) {
        int e = t * 64 + lane;
        int di = e >> 5, dj = e & 31;
        float dx = __fsub_rn(s_gx[w][di], s_gx[w][dj]);
        float dy = __fsub_rn(s_gy[w][di], s_gy[w][dj]);
        float dz = __fsub_rn(s_gz[w][di], s_gz[w][dj]);
        s_dis[w][di][dj] =
            sqrtf(__fadd_rn(__fadd_rn(__fmul_rn(dx, dx), __fmul_rn(dy, dy)), __fmul_rn(dz, dz)));
    }
    __syncthreads();

    {
        int i = lane & 31;
        float r[8];
        #pragma unroll
        for (int t = 0; t < 8; ++t) {
            r[t] = __fadd_rn(__fadd_rn(__fadd_rn(s_dis[w][i][t], s_dis[w][i][t + 8]),
                                        s_dis[w][i][t + 16]),
                             s_dis[w][i][t + 24]);
        }
        float mv = __fadd_rn(__fadd_rn(__fadd_rn(r[0], r[1]), __fadd_rn(r[2], r[3])),
                             __fadd_rn(__fadd_rn(r[4], r[5]), __fadd_rn(r[6], r[7])));
        int mi = i;
        #pragma unroll
        for (int off = 1; off < 64; off <<= 1) {
            float ov = __shfl_xor(mv, off);
            int oi = __shfl_xor(mi, off);
            if (ov > mv || (ov == mv && oi < mi)) { mv = ov; mi = oi; }
        }
        float tx = s_gx[w][mi], ty = s_gy[w][mi], tz = s_gz[w][mi];
        float ux = cy * tz - cz * ty, uy = cz * tx - cx * tz, uz = cx * ty - cy * tx;
        float vx = uy * cz - uz * cy, vy = uz * cx - ux * cz, vz = ux * cy - uy * cx;
        float vn = fmaxf(sqrtf(vx * vx + vy * vy + vz * vz), 1e-37f);
        float tnx = vx / vn, tny = vy / vn, tnz = vz / vn;
        float nr = sqrtf(cx * cx + cy * cy + cz * cz);
        float dn = nr + 1e-8f;
        float nnx = cx / dn, nny = cy / dn, nnz = cz / dn;
        int j = lane & 31;
        float gx = s_gx[w][j], gy = s_gy[w][j], gz = s_gz[w][j];
        float ax = cy * gz - cz * gy, ay = cz * gx - cx * gz, az = cx * gy - cy * gx;
        float px = ay * cz - az * cy, py = az * cx - ax * cz, pz = ax * cy - ay * cx;
        float pn = fmaxf(sqrtf(px * px + py * py + pz * pz), 1e-37f);
        px /= pn; py /= pn; pz /= pn;
        float qx = py * tnz - pz * tny;
        float qy = pz * tnx - px * tnz;
        float qz = px * tny - py * tnx;
        float sinv = qx * nnx + qy * nny + qz * nnz;
        float gr = sqrtf(gx * gx + gy * gy + gz * gz);
        const size_t rowstride = (size_t)MM * NS;
        const size_t obase = (((size_t)b * 33) * MM + m) * NS + j;
        if (lane < NS) out[obase + 32 * rowstride] = gr;
        float v[NS];
        #pragma unroll
        for (int ii = 0; ii < NS; ++ii) v[ii] = s_dis[w][ii][j];
        #pragma unroll
        for (int k = 2; k <= NS; k <<= 1) {
            #pragma unroll
            for (int jj = k >> 1; jj > 0; jj >>= 1) {
                #pragma unroll
                for (int ii = 0; ii < NS; ++ii) {
                    int ll = ii ^ jj;
                    if (ll > ii) {
                        bool up = ((ii & k) == 0);
                        float a = v[ii], c2 = v[ll];
                        bool sw = up ? (a > c2) : (a < c2);
                        if (sw) { v[ii] = c2; v[ll] = a; }
                    }
                }
            }
        }
        if (lane < NS) {
            #pragma unroll
            for (int ii = 0; ii < NS; ++ii)
                out[obase + (size_t)ii * rowstride] = v[ii] * sinv;
        }
    }
}

extern "C" void kernel_launch(void* const* d_in, const int* in_sizes, int n_in,
                              void* d_out, int out_size, void* d_ws, size_t ws_size,
                              hipStream_t stream) {
    (void)in_sizes; (void)n_in; (void)out_size;
    const float* xyz = (const float*)d_in[0];
    const float* nxyz = (const float*)d_in[1];
    float* out = (float*)d_out;

    if (d_ws != nullptr && ws_size >= WS_NEED) {
        char* ws = (char*)d_ws;
        int* off = (int*)ws;
        int* cur = (int*)(ws + WS_CUR_OFF);
        float4* pts = (float4*)(ws + WS_PTS_OFF);

        // build (R15-identical)
        k_count_scan<<<BB, 1024, 0, stream>>>(xyz, off, cur);
        k_scatter<<<(BB * NN) / 256, 256, 0, stream>>>(xyz, cur, pts);
        // 8192 queries, 8 per block (512 thr): phase1 1q/wave, phase2 pairs
        qgr_grid_kernel<<<(BB * MM) / 8, 512, 0, stream>>>(xyz, nxyz, off, pts, out);
    } else {
        qgr_kernel<<<(BB * MM) / 4, 256, 0, stream>>>(xyz, nxyz, out);
    }
}